// Round 4
// baseline (445.287 us; speedup 1.0000x reference)
//
#include <hip/hip_runtime.h>
#include <hip/hip_bf16.h>
#include <math.h>

#define B_TOTAL 8192
#define NN      82
#define HH      10
#define OUTC    5
#define TSTEP   3
#define NB      3            // batches per block
#define THREADS 256
#define KP      96           // padded K (j) dim: 3 x 32
#define MP      16           // padded per-batch row dim (h: 10 -> 16)

typedef __bf16 bf16x8 __attribute__((ext_vector_type(8)));
typedef float  f32x4  __attribute__((ext_vector_type(4)));

__device__ __forceinline__ float sigmoid_(float x) {
    return 1.0f / (1.0f + __expf(-x));
}
__device__ __forceinline__ float tanh_(float x) {
    float e = __expf(2.0f * x);
    return 1.0f - 2.0f / (e + 1.0f);
}

// adjP layout (bf16, each 96x96 zero-padded):
//   [0]: in_adj hi   [1]: out_adj hi   [2]: in_adj lo   [3]: out_adj lo
// Row-major adj[i][j] IS the MFMA B-operand layout (lane n=i reads 8 contiguous j).
__global__ void prep_adj_kernel(const float* __restrict__ in_adj,
                                const float* __restrict__ out_adj,
                                __hip_bfloat16* __restrict__ adjP) {
    int idx = blockIdx.x * blockDim.x + threadIdx.x;
    if (idx < 2 * KP * KP) {
        int a   = idx / (KP * KP);
        int rem = idx - a * (KP * KP);
        int i = rem / KP;
        int j = rem - i * KP;
        float v = 0.0f;
        if (i < NN && j < NN) v = (a == 0) ? in_adj[i * NN + j] : out_adj[i * NN + j];
        __hip_bfloat16 hi = __float2bfloat16(v);
        __hip_bfloat16 lo = __float2bfloat16(v - __bfloat162float(hi));
        adjP[idx]               = hi;
        adjP[2 * KP * KP + idx] = lo;
    }
}

// R1-verified per-thread GRU cell update (reference reuses w3u in rv — kept).
__device__ __forceinline__ void gru_update(
    float fn[HH], const float ai[HH], const float ao[HH],
    const float* __restrict__ w3w, const float* __restrict__ b3w,
    const float* __restrict__ w3u, const float* __restrict__ b3u,
    const float* __restrict__ w4w, const float* __restrict__ b4w,
    const float* __restrict__ w5w, const float* __restrict__ b5w,
    const float* __restrict__ w5u, const float* __restrict__ b5u)
{
    float u3[HH];
    #pragma unroll
    for (int h = 0; h < HH; ++h) {
        float s = b3u[h];
        #pragma unroll
        for (int k = 0; k < HH; ++k) s = fmaf(w3u[h * HH + k], fn[k], s);
        u3[h] = s;
    }

    float zv[HH], rv[HH];
    #pragma unroll
    for (int h = 0; h < HH; ++h) {
        float s1 = b3w[h];
        float s2 = b4w[h];
        #pragma unroll
        for (int k = 0; k < HH; ++k) {
            s1 = fmaf(w3w[h * 2 * HH + k],      ai[k], s1);
            s1 = fmaf(w3w[h * 2 * HH + HH + k], ao[k], s1);
            s2 = fmaf(w4w[h * 2 * HH + k],      ai[k], s2);
            s2 = fmaf(w4w[h * 2 * HH + HH + k], ao[k], s2);
        }
        zv[h] = sigmoid_(s1 + u3[h]);
        rv[h] = sigmoid_(s2 + u3[h]);
    }

    float rf[HH];
    #pragma unroll
    for (int k = 0; k < HH; ++k) rf[k] = rv[k] * fn[k];

    #pragma unroll
    for (int h = 0; h < HH; ++h) {
        float s = b5w[h] + b5u[h];
        #pragma unroll
        for (int k = 0; k < HH; ++k) {
            s = fmaf(w5w[h * 2 * HH + k],      ai[k], s);
            s = fmaf(w5w[h * 2 * HH + HH + k], ao[k], s);
            s = fmaf(w5u[h * HH + k],          rf[k], s);
        }
        float hv = tanh_(s);
        fn[h] = fn[h] + zv[h] * (hv - fn[h]);
    }
}

extern "C" __global__ __launch_bounds__(THREADS)
void ggnn_kernel(const float* __restrict__ x,
                 const __hip_bfloat16* __restrict__ adjP,
                 const float* __restrict__ w3w, const float* __restrict__ b3w,
                 const float* __restrict__ w3u, const float* __restrict__ b3u,
                 const float* __restrict__ w4w, const float* __restrict__ b4w,
                 const float* __restrict__ w5w, const float* __restrict__ b5w,
                 const float* __restrict__ w5u, const float* __restrict__ b5u,
                 const float* __restrict__ wout, const float* __restrict__ bout,
                 float* __restrict__ out0, float* __restrict__ out_fn)
{
    // Node states transposed, bf16 hi/lo split: Xt[b_l*16 + h][j]
    __shared__ __align__(16) __hip_bfloat16 XtH[NB * MP][KP];   // 9216 B
    __shared__ __align__(16) __hip_bfloat16 XtL[NB * MP][KP];   // 9216 B
    // Aggregation output (fp32): rows = b_l*82 + i, cols = h (pad 12)
    __shared__ __align__(16) float uin [NB * NN][12];           // 11808 B
    __shared__ __align__(16) float uout[NB * NN][12];           // 11808 B

    const int t     = threadIdx.x;
    const int bbase = blockIdx.x * NB;
    const int bl    = t / NN;            // 0..2 GRU-active, 3 = spare lanes
    const int node  = t - bl * NN;
    const bool act  = (bl < NB) && (bbase + bl < B_TOTAL);
    const int b     = bbase + bl;

    const int lane = t & 63;
    const int w    = t >> 6;             // wave id 0..3
    const int lo16 = lane & 15;
    const int quad = lane >> 4;

    // ---- initial fill of XtH/XtL from x (coalesced read, scattered b16 write) ----
    for (int idx = t; idx < NB * NN * HH; idx += THREADS) {
        int b_l = idx / (NN * HH);
        int rem = idx - b_l * (NN * HH);
        int j   = rem / HH;
        int h   = rem - j * HH;
        size_t g = (size_t)bbase * NN * HH + idx;
        float v = (g < (size_t)B_TOTAL * NN * HH) ? x[g] : 0.0f;
        __hip_bfloat16 hi = __float2bfloat16(v);
        __hip_bfloat16 lo = __float2bfloat16(v - __bfloat162float(hi));
        XtH[b_l * MP + h][j] = hi;
        XtL[b_l * MP + h][j] = lo;
    }
    // zero the K-pad columns (j = 82..95) for every row
    for (int idx = t; idx < NB * MP * (KP - NN); idx += THREADS) {
        int r = idx / (KP - NN);
        int c = idx - r * (KP - NN);
        __hip_bfloat16 z = __float2bfloat16(0.0f);
        XtH[r][NN + c] = z;
        XtL[r][NN + c] = z;
    }

    // ---- per-thread GRU state from x ----
    float fn[HH];
    if (act) {
        const float* xr = x + ((size_t)b * NN + node) * HH;   // 40B rows -> 8B aligned
        #pragma unroll
        for (int h2 = 0; h2 < HH / 2; ++h2) {
            float2 p = reinterpret_cast<const float2*>(xr)[h2];
            fn[2 * h2]     = p.x;
            fn[2 * h2 + 1] = p.y;
        }
    }

    for (int step = 0; step < TSTEP; ++step) {
        __syncthreads();   // Xt writes visible

        // ---- aggregation via MFMA: 36 C-frags (mtile3 x ntile6 x adj2), 9/wave ----
        for (int q = 0; q < 9; ++q) {
            int f     = w * 9 + q;
            int mtile = f / 12;
            int rem   = f - mtile * 12;
            int ntile = rem >> 1;
            int adj   = rem & 1;

            const __hip_bfloat16* Ah = &XtH[mtile * MP + lo16][quad * 8];
            const __hip_bfloat16* Al = &XtL[mtile * MP + lo16][quad * 8];
            const __hip_bfloat16* BpH = adjP + ((size_t)adj * KP * KP
                                                + (size_t)(ntile * 16 + lo16) * KP
                                                + quad * 8);
            const __hip_bfloat16* BpL = BpH + 2 * KP * KP;
            f32x4 acc = {0.0f, 0.0f, 0.0f, 0.0f};
            #pragma unroll
            for (int k = 0; k < 3; ++k) {
                bf16x8 ah = *reinterpret_cast<const bf16x8*>(Ah + k * 32);
                bf16x8 al = *reinterpret_cast<const bf16x8*>(Al + k * 32);
                bf16x8 bh = *reinterpret_cast<const bf16x8*>(BpH + k * 32);
                bf16x8 bl_ = *reinterpret_cast<const bf16x8*>(BpL + k * 32);
                acc = __builtin_amdgcn_mfma_f32_16x16x32_bf16(ah, bh, acc, 0, 0, 0);
                acc = __builtin_amdgcn_mfma_f32_16x16x32_bf16(al, bh, acc, 0, 0, 0);
                acc = __builtin_amdgcn_mfma_f32_16x16x32_bf16(ah, bl_, acc, 0, 0, 0);
            }
            // C element (reg r) = av[b=mtile][i = ntile*16+lo16][h = quad*4+r]
            int i = ntile * 16 + lo16;
            if (i < NN) {
                float* dst = (adj ? &uout[0][0] : &uin[0][0]) + (mtile * NN + i) * 12;
                if (quad < 2) {
                    *reinterpret_cast<float4*>(dst + quad * 4) =
                        make_float4(acc[0], acc[1], acc[2], acc[3]);
                } else if (quad == 2) {
                    *reinterpret_cast<float2*>(dst + 8) = make_float2(acc[0], acc[1]);
                }
                // quad 3 = h 12..15 pad, discarded
            }
        }

        __syncthreads();   // av visible

        // ---- per-thread GRU ----
        if (act) {
            float ai[HH], ao[HH];
            const float* ui = &uin [bl * NN + node][0];
            const float* uo = &uout[bl * NN + node][0];
            {
                float4 p0 = *reinterpret_cast<const float4*>(ui);
                float4 p1 = *reinterpret_cast<const float4*>(ui + 4);
                float2 p2 = *reinterpret_cast<const float2*>(ui + 8);
                ai[0]=p0.x; ai[1]=p0.y; ai[2]=p0.z; ai[3]=p0.w;
                ai[4]=p1.x; ai[5]=p1.y; ai[6]=p1.z; ai[7]=p1.w;
                ai[8]=p2.x; ai[9]=p2.y;
                float4 q0 = *reinterpret_cast<const float4*>(uo);
                float4 q1 = *reinterpret_cast<const float4*>(uo + 4);
                float2 q2 = *reinterpret_cast<const float2*>(uo + 8);
                ao[0]=q0.x; ao[1]=q0.y; ao[2]=q0.z; ao[3]=q0.w;
                ao[4]=q1.x; ao[5]=q1.y; ao[6]=q1.z; ao[7]=q1.w;
                ao[8]=q2.x; ao[9]=q2.y;
            }
            gru_update(fn, ai, ao, w3w, b3w, w3u, b3u, w4w, b4w, w5w, b5w, w5u, b5u);

            // publish new state into Xt (hi/lo) for next step's aggregation
            #pragma unroll
            for (int h = 0; h < HH; ++h) {
                __hip_bfloat16 hi = __float2bfloat16(fn[h]);
                __hip_bfloat16 lo = __float2bfloat16(fn[h] - __bfloat162float(hi));
                XtH[bl * MP + h][node] = hi;
                XtL[bl * MP + h][node] = lo;
            }
        }
    }

    // ---- epilogue: out0 = tanh([fn, x] @ wout^T + bout), out_fn = fn ----
    if (act) {
        size_t row = (size_t)b * NN + node;
        const float* xr = x + row * HH;
        float xi[HH];
        #pragma unroll
        for (int h2 = 0; h2 < HH / 2; ++h2) {
            float2 p = reinterpret_cast<const float2*>(xr)[h2];
            xi[2 * h2]     = p.x;
            xi[2 * h2 + 1] = p.y;
        }

        #pragma unroll
        for (int c = 0; c < OUTC; ++c) {
            float s = bout[c];
            #pragma unroll
            for (int k = 0; k < HH; ++k) s = fmaf(wout[c * 2 * HH + k],      fn[k], s);
            #pragma unroll
            for (int k = 0; k < HH; ++k) s = fmaf(wout[c * 2 * HH + HH + k], xi[k], s);
            out0[row * OUTC + c] = tanh_(s);
        }
        #pragma unroll
        for (int h2 = 0; h2 < HH / 2; ++h2) {
            reinterpret_cast<float2*>(out_fn + row * HH)[h2] =
                make_float2(fn[2 * h2], fn[2 * h2 + 1]);
        }
    }
}

extern "C" void kernel_launch(void* const* d_in, const int* in_sizes, int n_in,
                              void* d_out, int out_size, void* d_ws, size_t ws_size,
                              hipStream_t stream) {
    const float* x       = (const float*)d_in[0];
    const float* in_adj  = (const float*)d_in[1];
    const float* out_adj = (const float*)d_in[2];
    const float* w3w = (const float*)d_in[3];
    const float* b3w = (const float*)d_in[4];
    const float* w3u = (const float*)d_in[5];
    const float* b3u = (const float*)d_in[6];
    const float* w4w = (const float*)d_in[7];
    const float* b4w = (const float*)d_in[8];
    const float* w5w = (const float*)d_in[9];
    const float* b5w = (const float*)d_in[10];
    const float* w5u = (const float*)d_in[11];
    const float* b5u = (const float*)d_in[12];
    const float* wout = (const float*)d_in[13];
    const float* bout = (const float*)d_in[14];

    __hip_bfloat16* adjP = (__hip_bfloat16*)d_ws;   // 4*96*96*2 = 73.7 KB
    float* out0   = (float*)d_out;
    float* out_fn = out0 + (size_t)B_TOTAL * NN * OUTC;

    prep_adj_kernel<<<(2 * KP * KP + 255) / 256, 256, 0, stream>>>(in_adj, out_adj, adjP);

    int grid = (B_TOTAL + NB - 1) / NB;             // 2731
    ggnn_kernel<<<grid, THREADS, 0, stream>>>(
        x, adjP, w3w, b3w, w3u, b3u, w4w, b4w, w5w, b5w, w5u, b5u,
        wout, bout, out0, out_fn);
}

// Round 5
// 268.316 us; speedup vs baseline: 1.6596x; 1.6596x over previous
//
#include <hip/hip_runtime.h>
#include <hip/hip_bf16.h>
#include <math.h>

#define B_TOTAL 8192
#define NN      82
#define HH      10
#define OUTC    5
#define TSTEP   3
#define NB      3            // batches per block
#define THREADS 256
#define KP      96           // padded K (j) dim: 3 x 32
#define MP      16           // padded per-batch row dim (h: 10 -> 16)
#define XS      104          // Xt row stride in bf16: 208 B = 52 words (= 20 mod 32, 16B-aligned)

typedef __bf16 bf16x8 __attribute__((ext_vector_type(8)));
typedef float  f32x4  __attribute__((ext_vector_type(4)));

__device__ __forceinline__ float sigmoid_(float x) {
    return 1.0f / (1.0f + __expf(-x));
}
__device__ __forceinline__ float tanh_(float x) {
    float e = __expf(2.0f * x);
    return 1.0f - 2.0f / (e + 1.0f);
}

// adjP layout (bf16, each 96x96 zero-padded):
//   [0]: in_adj hi   [1]: out_adj hi   [2]: in_adj lo   [3]: out_adj lo
// Row-major adj[i][j] IS the MFMA B-operand layout (lane n=i reads 8 contiguous j).
__global__ void prep_adj_kernel(const float* __restrict__ in_adj,
                                const float* __restrict__ out_adj,
                                __hip_bfloat16* __restrict__ adjP) {
    int idx = blockIdx.x * blockDim.x + threadIdx.x;
    if (idx < 2 * KP * KP) {
        int a   = idx / (KP * KP);
        int rem = idx - a * (KP * KP);
        int i = rem / KP;
        int j = rem - i * KP;
        float v = 0.0f;
        if (i < NN && j < NN) v = (a == 0) ? in_adj[i * NN + j] : out_adj[i * NN + j];
        __hip_bfloat16 hi = __float2bfloat16(v);
        __hip_bfloat16 lo = __float2bfloat16(v - __bfloat162float(hi));
        adjP[idx]               = hi;
        adjP[2 * KP * KP + idx] = lo;
    }
}

// R1-verified per-thread GRU cell update (reference reuses w3u in rv — kept).
__device__ __forceinline__ void gru_update(
    float fn[HH], const float ai[HH], const float ao[HH],
    const float* __restrict__ w3w, const float* __restrict__ b3w,
    const float* __restrict__ w3u, const float* __restrict__ b3u,
    const float* __restrict__ w4w, const float* __restrict__ b4w,
    const float* __restrict__ w5w, const float* __restrict__ b5w,
    const float* __restrict__ w5u, const float* __restrict__ b5u)
{
    float u3[HH];
    #pragma unroll
    for (int h = 0; h < HH; ++h) {
        float s = b3u[h];
        #pragma unroll
        for (int k = 0; k < HH; ++k) s = fmaf(w3u[h * HH + k], fn[k], s);
        u3[h] = s;
    }

    float zv[HH], rv[HH];
    #pragma unroll
    for (int h = 0; h < HH; ++h) {
        float s1 = b3w[h];
        float s2 = b4w[h];
        #pragma unroll
        for (int k = 0; k < HH; ++k) {
            s1 = fmaf(w3w[h * 2 * HH + k],      ai[k], s1);
            s1 = fmaf(w3w[h * 2 * HH + HH + k], ao[k], s1);
            s2 = fmaf(w4w[h * 2 * HH + k],      ai[k], s2);
            s2 = fmaf(w4w[h * 2 * HH + HH + k], ao[k], s2);
        }
        zv[h] = sigmoid_(s1 + u3[h]);
        rv[h] = sigmoid_(s2 + u3[h]);
    }

    float rf[HH];
    #pragma unroll
    for (int k = 0; k < HH; ++k) rf[k] = rv[k] * fn[k];

    #pragma unroll
    for (int h = 0; h < HH; ++h) {
        float s = b5w[h] + b5u[h];
        #pragma unroll
        for (int k = 0; k < HH; ++k) {
            s = fmaf(w5w[h * 2 * HH + k],      ai[k], s);
            s = fmaf(w5w[h * 2 * HH + HH + k], ao[k], s);
            s = fmaf(w5u[h * HH + k],          rf[k], s);
        }
        float hv = tanh_(s);
        fn[h] = fn[h] + zv[h] * (hv - fn[h]);
    }
}

extern "C" __global__ __launch_bounds__(THREADS)
void ggnn_kernel(const float* __restrict__ x,
                 const __hip_bfloat16* __restrict__ adjP,
                 const float* __restrict__ w3w, const float* __restrict__ b3w,
                 const float* __restrict__ w3u, const float* __restrict__ b3u,
                 const float* __restrict__ w4w, const float* __restrict__ b4w,
                 const float* __restrict__ w5w, const float* __restrict__ b5w,
                 const float* __restrict__ w5u, const float* __restrict__ b5u,
                 const float* __restrict__ wout, const float* __restrict__ bout,
                 float* __restrict__ out0, float* __restrict__ out_fn)
{
    // Node states transposed, bf16 hi/lo split: Xt[b_l*16 + h][j], stride XS=104
    __shared__ __align__(16) __hip_bfloat16 XtH[NB * MP][XS];   // 9984 B
    __shared__ __align__(16) __hip_bfloat16 XtL[NB * MP][XS];   // 9984 B
    // Aggregation output (fp32): rows = b_l*82 + i, cols = h (pad 12)
    __shared__ __align__(16) float uin [NB * NN][12];           // 11808 B
    __shared__ __align__(16) float uout[NB * NN][12];           // 11808 B

    const int t     = threadIdx.x;
    const int bbase = blockIdx.x * NB;
    const int bl    = t / NN;            // 0..2 GRU-active, 3 = spare lanes
    const int node  = t - bl * NN;
    const bool act  = (bl < NB) && (bbase + bl < B_TOTAL);
    const int b     = bbase + bl;

    const int lane = t & 63;
    const int w    = t >> 6;             // wave id 0..3
    const int lo16 = lane & 15;
    const int quad = lane >> 4;

    // ---- preload this wave's 3 (ntile,adj) B-combos into registers (step-invariant) ----
    // combo co = ntile*2 + adj; wave w owns co = 3w .. 3w+2.
    bf16x8 Bh[3][3], Bl[3][3];           // [combo][k-slab] : 72 VGPRs
    int ntile_c[3], adj_c[3];
    #pragma unroll
    for (int c = 0; c < 3; ++c) {
        int co = w * 3 + c;
        int nt = co >> 1;
        int ad = co & 1;
        ntile_c[c] = nt;
        adj_c[c]   = ad;
        const __hip_bfloat16* BpH = adjP + ((size_t)ad * KP * KP
                                            + (size_t)(nt * 16 + lo16) * KP
                                            + quad * 8);
        #pragma unroll
        for (int k = 0; k < 3; ++k) {
            Bh[c][k] = *reinterpret_cast<const bf16x8*>(BpH + k * 32);
            Bl[c][k] = *reinterpret_cast<const bf16x8*>(BpH + 2 * KP * KP + k * 32);
        }
    }

    // ---- initial fill of XtH/XtL from x (coalesced read) ----
    for (int idx = t; idx < NB * NN * HH; idx += THREADS) {
        int b_l = idx / (NN * HH);
        int rem = idx - b_l * (NN * HH);
        int j   = rem / HH;
        int h   = rem - j * HH;
        size_t g = (size_t)bbase * NN * HH + idx;
        float v = (g < (size_t)B_TOTAL * NN * HH) ? x[g] : 0.0f;
        __hip_bfloat16 hi = __float2bfloat16(v);
        __hip_bfloat16 lo = __float2bfloat16(v - __bfloat162float(hi));
        XtH[b_l * MP + h][j] = hi;
        XtL[b_l * MP + h][j] = lo;
    }
    // zero the K-pad columns (j = 82..95) for every row
    for (int idx = t; idx < NB * MP * (KP - NN); idx += THREADS) {
        int r = idx / (KP - NN);
        int c = idx - r * (KP - NN);
        __hip_bfloat16 z = __float2bfloat16(0.0f);
        XtH[r][NN + c] = z;
        XtL[r][NN + c] = z;
    }

    // ---- per-thread GRU state from x ----
    float fn[HH];
    if (act) {
        const float* xr = x + ((size_t)b * NN + node) * HH;
        #pragma unroll
        for (int h2 = 0; h2 < HH / 2; ++h2) {
            float2 p = reinterpret_cast<const float2*>(xr)[h2];
            fn[2 * h2]     = p.x;
            fn[2 * h2 + 1] = p.y;
        }
    }

    for (int step = 0; step < TSTEP; ++step) {
        __syncthreads();   // Xt writes visible

        // ---- aggregation via MFMA: A from LDS (reused across combos), B from regs ----
        #pragma unroll
        for (int mtile = 0; mtile < NB; ++mtile) {
            f32x4 acc[3] = {{0,0,0,0}, {0,0,0,0}, {0,0,0,0}};
            #pragma unroll
            for (int k = 0; k < 3; ++k) {
                bf16x8 ah = *reinterpret_cast<const bf16x8*>(&XtH[mtile * MP + lo16][quad * 8 + k * 32]);
                bf16x8 al = *reinterpret_cast<const bf16x8*>(&XtL[mtile * MP + lo16][quad * 8 + k * 32]);
                #pragma unroll
                for (int c = 0; c < 3; ++c) {
                    acc[c] = __builtin_amdgcn_mfma_f32_16x16x32_bf16(ah, Bh[c][k], acc[c], 0, 0, 0);
                    acc[c] = __builtin_amdgcn_mfma_f32_16x16x32_bf16(al, Bh[c][k], acc[c], 0, 0, 0);
                    acc[c] = __builtin_amdgcn_mfma_f32_16x16x32_bf16(ah, Bl[c][k], acc[c], 0, 0, 0);
                }
            }
            // C element (reg r) = av[b=mtile][i = ntile*16+lo16][h = quad*4+r]
            #pragma unroll
            for (int c = 0; c < 3; ++c) {
                int i = ntile_c[c] * 16 + lo16;
                if (i < NN) {
                    float* dst = (adj_c[c] ? &uout[0][0] : &uin[0][0]) + (mtile * NN + i) * 12;
                    if (quad < 2) {
                        *reinterpret_cast<float4*>(dst + quad * 4) =
                            make_float4(acc[c][0], acc[c][1], acc[c][2], acc[c][3]);
                    } else if (quad == 2) {
                        *reinterpret_cast<float2*>(dst + 8) = make_float2(acc[c][0], acc[c][1]);
                    }
                    // quad 3 = h 12..15 pad, discarded
                }
            }
        }

        __syncthreads();   // av visible

        // ---- per-thread GRU ----
        if (act) {
            float ai[HH], ao[HH];
            const float* ui = &uin [bl * NN + node][0];
            const float* uo = &uout[bl * NN + node][0];
            {
                float4 p0 = *reinterpret_cast<const float4*>(ui);
                float4 p1 = *reinterpret_cast<const float4*>(ui + 4);
                float2 p2 = *reinterpret_cast<const float2*>(ui + 8);
                ai[0]=p0.x; ai[1]=p0.y; ai[2]=p0.z; ai[3]=p0.w;
                ai[4]=p1.x; ai[5]=p1.y; ai[6]=p1.z; ai[7]=p1.w;
                ai[8]=p2.x; ai[9]=p2.y;
                float4 q0 = *reinterpret_cast<const float4*>(uo);
                float4 q1 = *reinterpret_cast<const float4*>(uo + 4);
                float2 q2 = *reinterpret_cast<const float2*>(uo + 8);
                ao[0]=q0.x; ao[1]=q0.y; ao[2]=q0.z; ao[3]=q0.w;
                ao[4]=q1.x; ao[5]=q1.y; ao[6]=q1.z; ao[7]=q1.w;
                ao[8]=q2.x; ao[9]=q2.y;
            }
            gru_update(fn, ai, ao, w3w, b3w, w3u, b3u, w4w, b4w, w5w, b5w, w5u, b5u);

            // publish new state into Xt (hi/lo) for next step's aggregation
            #pragma unroll
            for (int h = 0; h < HH; ++h) {
                __hip_bfloat16 hi = __float2bfloat16(fn[h]);
                __hip_bfloat16 lo = __float2bfloat16(fn[h] - __bfloat162float(hi));
                XtH[bl * MP + h][node] = hi;
                XtL[bl * MP + h][node] = lo;
            }
        }
    }

    // ---- epilogue: out0 = tanh([fn, x] @ wout^T + bout), out_fn = fn ----
    if (act) {
        size_t row = (size_t)b * NN + node;
        const float* xr = x + row * HH;
        float xi[HH];
        #pragma unroll
        for (int h2 = 0; h2 < HH / 2; ++h2) {
            float2 p = reinterpret_cast<const float2*>(xr)[h2];
            xi[2 * h2]     = p.x;
            xi[2 * h2 + 1] = p.y;
        }

        #pragma unroll
        for (int c = 0; c < OUTC; ++c) {
            float s = bout[c];
            #pragma unroll
            for (int k = 0; k < HH; ++k) s = fmaf(wout[c * 2 * HH + k],      fn[k], s);
            #pragma unroll
            for (int k = 0; k < HH; ++k) s = fmaf(wout[c * 2 * HH + HH + k], xi[k], s);
            out0[row * OUTC + c] = tanh_(s);
        }
        #pragma unroll
        for (int h2 = 0; h2 < HH / 2; ++h2) {
            reinterpret_cast<float2*>(out_fn + row * HH)[h2] =
                make_float2(fn[2 * h2], fn[2 * h2 + 1]);
        }
    }
}

extern "C" void kernel_launch(void* const* d_in, const int* in_sizes, int n_in,
                              void* d_out, int out_size, void* d_ws, size_t ws_size,
                              hipStream_t stream) {
    const float* x       = (const float*)d_in[0];
    const float* in_adj  = (const float*)d_in[1];
    const float* out_adj = (const float*)d_in[2];
    const float* w3w = (const float*)d_in[3];
    const float* b3w = (const float*)d_in[4];
    const float* w3u = (const float*)d_in[5];
    const float* b3u = (const float*)d_in[6];
    const float* w4w = (const float*)d_in[7];
    const float* b4w = (const float*)d_in[8];
    const float* w5w = (const float*)d_in[9];
    const float* b5w = (const float*)d_in[10];
    const float* w5u = (const float*)d_in[11];
    const float* b5u = (const float*)d_in[12];
    const float* wout = (const float*)d_in[13];
    const float* bout = (const float*)d_in[14];

    __hip_bfloat16* adjP = (__hip_bfloat16*)d_ws;   // 4*96*96*2 = 73.7 KB
    float* out0   = (float*)d_out;
    float* out_fn = out0 + (size_t)B_TOTAL * NN * OUTC;

    prep_adj_kernel<<<(2 * KP * KP + 255) / 256, 256, 0, stream>>>(in_adj, out_adj, adjP);

    int grid = (B_TOTAL + NB - 1) / NB;             // 2731
    ggnn_kernel<<<grid, THREADS, 0, stream>>>(
        x, adjP, w3w, b3w, w3u, b3u, w4w, b4w, w5w, b5w, w5u, b5u,
        wout, bout, out0, out_fn);
}